// Round 7
// baseline (78.935 us; speedup 1.0000x reference)
//
#include <hip/hip_runtime.h>

#define DENSE 2048
#define BATCH 64
#define MAXS  1024

typedef __attribute__((ext_vector_type(8))) __bf16 bf16x8;
typedef __attribute__((ext_vector_type(4))) float f32x4;

// ws: Cbf[b][k] bf16 counts in MFMA A-fragment order (verified R2, absmax 1.0):
//   lane = (b&15) | (((k>>3)&3)<<4) holds C[b = mt*16+(lane&15)][k = ks*32+(lane>>4)*8+i]
//   == A[m=lane&15][k=(lane>>4)*8+i] for mfma_f32_16x16x32_bf16.

// hist + W-prewarm. Blocks 0..63: per-batch histogram -> Cbf. Blocks 64..255:
// coalesced float4 read-through of W (16B/lane, full lines — NOT R5's 4B/64B
// stride) to pull W into L3 and absorb the dirty-poison evictions during this
// dispatch instead of spmm's critical path. No out-zeroing needed anymore.
__global__ __launch_bounds__(256) void hist_kernel(const int* __restrict__ ids,
                                                   const int* __restrict__ ns,
                                                   const float* __restrict__ W,
                                                   __bf16* __restrict__ Cbf,
                                                   float* __restrict__ guard) {
    const int tid = threadIdx.x;
    const int bid = blockIdx.x;
    if (bid < BATCH) {
        __shared__ int cnt[DENSE];
        const int b = bid;
        #pragma unroll
        for (int k = tid; k < DENSE; k += 256) cnt[k] = 0;
        __syncthreads();
        const int n = ns[b];
        const int4 v = ((const int4*)(ids + b * MAXS))[tid];   // 1024 = 256*int4
        const int base = tid * 4;
        if (base + 0 < n) atomicAdd(&cnt[v.x], 1);
        if (base + 1 < n) atomicAdd(&cnt[v.y], 1);
        if (base + 2 < n) atomicAdd(&cnt[v.z], 1);
        if (base + 3 < n) atomicAdd(&cnt[v.w], 1);
        __syncthreads();
        const int mt = b >> 4;
        const int bl = b & 15;
        #pragma unroll
        for (int k = tid; k < DENSE; k += 256) {
            const int lane = bl | (((k >> 3) & 3) << 4);
            const size_t off = (size_t)(((k >> 5) * 4 + mt) * 64 + lane) * 8 + (k & 7);
            Cbf[off] = (__bf16)(float)cnt[k];
        }
    } else {
        // W prewarm: grid-stride float4 stream over all of W (cached loads)
        const int t = (bid - BATCH) * 256 + tid;               // 0..49151
        float s = 0.0f;
        for (int i = t; i < (DENSE * DENSE) / 4; i += 192 * 256) {
            const f32x4 v = ((const f32x4*)W)[i];
            s += v.x + v.y + v.z + v.w;
        }
        if (s != s) guard[0] = s;   // never true (W finite); defeats DCE
    }
}

// spmm full-K: out[b][j] = sum_k C[b][k] * W[j][k], one block per 16-row
// j-tile (128 blocks), all k in-block -> plain stores, NO atomics/zeroing.
// Wave wv covers k-steps [wv*16, wv*16+16), 4 chunks of 4 steps with a
// depth-2 register pipeline (~220 VGPR; launch_bounds(256,1) allows it —
// only 4 waves/CU resident so VGPR is free).
__global__ __launch_bounds__(256, 1) void spmm_kernel(const float* __restrict__ W,
                                                      const __bf16* __restrict__ Cbf,
                                                      float* __restrict__ out) {
    const int tid  = threadIdx.x;
    const int lane = tid & 63;
    const int wv   = tid >> 6;          // 0..3
    const int j0   = blockIdx.x * 16;

    const int ln = lane & 15;           // j index (B-frag n)
    const int lq = lane >> 4;           // k quad

    const float* wrow = W + (size_t)(j0 + ln) * DENSE;
    const int ks0 = wv * 16;

    f32x4  w0[2][4], w1[2][4];
    bf16x8 ca[2][4][4];

    // prologue: chunk 0
    #pragma unroll
    for (int s = 0; s < 4; ++s) {
        const int ks = ks0 + s;
        const int kb = ks * 32 + lq * 8;
        w0[0][s] = *(const f32x4*)(wrow + kb);
        w1[0][s] = *(const f32x4*)(wrow + kb + 4);
        #pragma unroll
        for (int mt = 0; mt < 4; ++mt)
            ca[0][s][mt] = *(const bf16x8*)(Cbf + ((size_t)(ks * 4 + mt) * 64 + lane) * 8);
    }

    f32x4 acc[4];
    #pragma unroll
    for (int mt = 0; mt < 4; ++mt) acc[mt] = (f32x4)0.0f;

    #pragma unroll
    for (int c = 0; c < 4; ++c) {
        const int cur = c & 1, nxt = cur ^ 1;
        if (c < 3) {                    // prefetch chunk c+1 (compile-time folded)
            #pragma unroll
            for (int s = 0; s < 4; ++s) {
                const int ks = ks0 + (c + 1) * 4 + s;
                const int kb = ks * 32 + lq * 8;
                w0[nxt][s] = *(const f32x4*)(wrow + kb);
                w1[nxt][s] = *(const f32x4*)(wrow + kb + 4);
                #pragma unroll
                for (int mt = 0; mt < 4; ++mt)
                    ca[nxt][s][mt] = *(const bf16x8*)(Cbf + ((size_t)(ks * 4 + mt) * 64 + lane) * 8);
            }
        }
        #pragma unroll
        for (int s = 0; s < 4; ++s) {
            bf16x8 wb;
            #pragma unroll
            for (int i = 0; i < 4; ++i) {
                wb[i]     = (__bf16)w0[cur][s][i];
                wb[i + 4] = (__bf16)w1[cur][s][i];
            }
            #pragma unroll
            for (int mt = 0; mt < 4; ++mt)
                acc[mt] = __builtin_amdgcn_mfma_f32_16x16x32_bf16(ca[cur][s][mt], wb, acc[mt], 0, 0, 0);
        }
    }

    // cross-wave LDS reduction, conflict-free P[wv][mt][r][lane]
    __shared__ float P[4][4][4][64];    // 16 KB
    #pragma unroll
    for (int mt = 0; mt < 4; ++mt) {
        #pragma unroll
        for (int r = 0; r < 4; ++r) {
            P[wv][mt][r][lane] = acc[mt][r];
        }
    }
    __syncthreads();

    // plain coalesced stores: thread t -> row b = t>>2, f32x4 group jq = t&3
    // (C/D layout: row m16 = (lane>>4)*4 + r, col = lane&15 — verified R2)
    const int b   = tid >> 2;           // 0..63
    const int jq  = tid & 3;
    const int mt  = b >> 4;
    const int m16 = b & 15;
    const int r   = m16 & 3;
    const int lh  = (m16 >> 2) << 4;
    f32x4 o;
    #pragma unroll
    for (int i = 0; i < 4; ++i) {
        const int lsrc = lh | (jq * 4 + i);
        o[i] = P[0][mt][r][lsrc] + P[1][mt][r][lsrc]
             + P[2][mt][r][lsrc] + P[3][mt][r][lsrc];
    }
    *(f32x4*)(out + (size_t)b * DENSE + j0 + jq * 4) = o;
}

extern "C" void kernel_launch(void* const* d_in, const int* in_sizes, int n_in,
                              void* d_out, int out_size, void* d_ws, size_t ws_size,
                              hipStream_t stream) {
    const int*   ids = (const int*)d_in[0];   // [64, 1024] int32
    const int*   ns  = (const int*)d_in[1];   // [64] int32
    const float* W   = (const float*)d_in[2]; // [2048, 2048] float32
    float*  out = (float*)d_out;              // [64, 2048] float32
    __bf16* Cbf = (__bf16*)d_ws;              // 64*2048 bf16 = 256 KB
    float*  guard = (float*)((char*)d_ws + (1 << 20));

    hipLaunchKernelGGL(hist_kernel, dim3(256), dim3(256), 0, stream, ids, ns, W, Cbf, guard);
    hipLaunchKernelGGL(spmm_kernel, dim3(128), dim3(256), 0, stream, W, Cbf, out);
}

// Round 8
// 72.410 us; speedup vs baseline: 1.0901x; 1.0901x over previous
//
#include <hip/hip_runtime.h>

#define DENSE 2048
#define BATCH 64
#define MAXS  1024

typedef __attribute__((ext_vector_type(8))) __bf16 bf16x8;
typedef __attribute__((ext_vector_type(4))) float f32x4;

// ws: Cbf[b][k] bf16 counts in MFMA A-fragment order (verified R2, absmax 1.0):
//   lane = (b&15) | (((k>>3)&3)<<4) holds C[b = mt*16+(lane&15)][k = ks*32+(lane>>4)*8+i]
//   == A[m=lane&15][k=(lane>>4)*8+i] for mfma_f32_16x16x32_bf16.
//
// R8 = verbatim R6 (best known, 72.16 µs). Session ledger:
//   R3 nontemporal-W: -2 µs (defeats L2 line pairing)      [reverted]
//   R4 split-K 8 + reduce kernel: -3 µs (extra node+traffic)[reverted]
//   R5 cooperative fusion: -49 µs (grid pinned, bad prewarm)[reverted]
//   R7 full-K 128 blocks + prewarm: -6.8 µs (half the CUs;  [reverted]
//      poison is clean in L3 after fill -> no eviction win)
// Whole-window model: ~48.5 µs harness memory work (268MB poison fill at
// HBM ceiling + restores) + ~14-16 µs graph-node overhead (8 nodes) +
// hist ~2.5 + spmm ~5. Controllable slack ~3-4 µs; all grabs regressed.

__global__ __launch_bounds__(256) void hist_kernel(const int* __restrict__ ids,
                                                   const int* __restrict__ ns,
                                                   __bf16* __restrict__ Cbf,
                                                   float* __restrict__ out) {
    __shared__ int cnt[DENSE];
    const int b = blockIdx.x;
    const int tid = threadIdx.x;
    #pragma unroll
    for (int k = tid; k < DENSE; k += 256) cnt[k] = 0;
    __syncthreads();
    const int n = ns[b];
    // 1024 spikes = exactly one int4 per thread
    const int4 v = ((const int4*)(ids + b * MAXS))[tid];
    const int base = tid * 4;
    if (base + 0 < n) atomicAdd(&cnt[v.x], 1);
    if (base + 1 < n) atomicAdd(&cnt[v.y], 1);
    if (base + 2 < n) atomicAdd(&cnt[v.z], 1);
    if (base + 3 < n) atomicAdd(&cnt[v.w], 1);
    __syncthreads();
    const int mt = b >> 4;
    const int bl = b & 15;
    #pragma unroll
    for (int k = tid; k < DENSE; k += 256) {
        const int lane = bl | (((k >> 3) & 3) << 4);
        const size_t off = (size_t)(((k >> 5) * 4 + mt) * 64 + lane) * 8 + (k & 7);
        Cbf[off] = (__bf16)(float)cnt[k];
        out[(size_t)b * DENSE + k] = 0.0f;   // zero output for spmm's atomics
    }
}

// spmm: out[b][j] += sum_k C[b][k] * W[j][k] via bf16 MFMA 16x16x32.
// grid (128 j-tiles, 4 k-splits) = 512 blocks (2/CU, all co-resident);
// 4 waves/block, 4 k-steps/wave, all 24 loads issued up front (one burst),
// conflict-free epilogue LDS layout, atomicAdd with 4 contenders/address.
__global__ __launch_bounds__(256) void spmm_kernel(const float* __restrict__ W,
                                                   const __bf16* __restrict__ Cbf,
                                                   float* __restrict__ out) {
    const int tid  = threadIdx.x;
    const int lane = tid & 63;
    const int wv   = tid >> 6;          // 0..3
    const int j0   = blockIdx.x * 16;   // j tile
    const int ks4  = blockIdx.y;        // 0..3 k split

    const int ln = lane & 15;           // j index within tile (B-frag n)
    const int lq = lane >> 4;           // k quad 0..3

    const int step0 = ks4 * 16 + wv * 4;
    const float* wrow = W + (size_t)(j0 + ln) * DENSE;

    // --- W loads first (HBM long pole; plain cached loads — NT regressed R3)
    f32x4 w0[4], w1[4];
    #pragma unroll
    for (int s = 0; s < 4; ++s) {
        const int kbase = (step0 + s) * 32 + lq * 8;
        w0[s] = *(const f32x4*)(wrow + kbase);
        w1[s] = *(const f32x4*)(wrow + kbase + 4);
    }
    // --- A-frag loads (Cbf is L2/L3-resident; R5 FETCH ≈ W only confirms)
    bf16x8 afr[4][4];
    #pragma unroll
    for (int s = 0; s < 4; ++s) {
        #pragma unroll
        for (int mt = 0; mt < 4; ++mt) {
            afr[s][mt] = *(const bf16x8*)(Cbf + ((size_t)((step0 + s) * 4 + mt) * 64 + lane) * 8);
        }
    }

    bf16x8 wb[4];
    #pragma unroll
    for (int s = 0; s < 4; ++s) {
        #pragma unroll
        for (int i = 0; i < 4; ++i) {
            wb[s][i]     = (__bf16)w0[s][i];
            wb[s][i + 4] = (__bf16)w1[s][i];
        }
    }

    f32x4 acc[4];
    #pragma unroll
    for (int mt = 0; mt < 4; ++mt) acc[mt] = (f32x4)0.0f;
    #pragma unroll
    for (int s = 0; s < 4; ++s) {
        #pragma unroll
        for (int mt = 0; mt < 4; ++mt) {
            acc[mt] = __builtin_amdgcn_mfma_f32_16x16x32_bf16(afr[s][mt], wb[s], acc[mt], 0, 0, 0);
        }
    }

    // --- cross-wave reduction, conflict-free layout P[wv][mt][r][lane]
    __shared__ float P[4][4][4][64];    // 16 KB
    #pragma unroll
    for (int mt = 0; mt < 4; ++mt) {
        #pragma unroll
        for (int r = 0; r < 4; ++r) {
            P[wv][mt][r][lane] = acc[mt][r];
        }
    }
    __syncthreads();

    // thread t -> (jloc = t&15 fastest for coalesced atomics, bpart = t>>4)
    const int jloc  = tid & 15;
    const int bpart = tid >> 4;                       // 0..15
    const int lsrc  = ((bpart >> 2) << 4) | jloc;     // source lane
    const int r     = bpart & 3;                      // source acc reg
    #pragma unroll
    for (int mt = 0; mt < 4; ++mt) {
        const float v = P[0][mt][r][lsrc] + P[1][mt][r][lsrc]
                      + P[2][mt][r][lsrc] + P[3][mt][r][lsrc];
        atomicAdd(&out[(size_t)(mt * 16 + bpart) * DENSE + j0 + jloc], v);
    }
}

extern "C" void kernel_launch(void* const* d_in, const int* in_sizes, int n_in,
                              void* d_out, int out_size, void* d_ws, size_t ws_size,
                              hipStream_t stream) {
    const int*   ids = (const int*)d_in[0];   // [64, 1024] int32
    const int*   ns  = (const int*)d_in[1];   // [64] int32
    const float* W   = (const float*)d_in[2]; // [2048, 2048] float32
    float*  out = (float*)d_out;              // [64, 2048] float32
    __bf16* Cbf = (__bf16*)d_ws;              // 64*2048 bf16 = 256 KB

    hipLaunchKernelGGL(hist_kernel, dim3(BATCH), dim3(256), 0, stream, ids, ns, Cbf, out);
    hipLaunchKernelGGL(spmm_kernel, dim3(128, 4), dim3(256), 0, stream, W, Cbf, out);
}